// Round 8
// baseline (158.715 us; speedup 1.0000x reference)
//
#include <hip/hip_runtime.h>

// CTC loss forward DP (Keras ctc_batch_cost), mean over batch.
// B=512, T=512, C=96 (blank=95), L=64. Lane i owns extended states 2i and
// 2i+1; lane 63 also owns state 128.
//
// R10: TWO EXAMPLES PER WAVE. 256 blocks x 64 threads; block b runs examples
// 2b and 2b+1 as two independent DP chains interleaved in one wave. Each
// chain's math is R6/R9-verbatim (cndmask step, SYNCHRONOUS renorm every 8 —
// the renorm floor is load-bearing, frozen). Rationale: R9's kernel is
// ~40us = 187cy/step vs ~45cy/step of modeled issue -> ~75% per-wave stall;
// a second independent chain in the same wave fills those stalls (2x if
// latency-bound, neutral if issue-bound).
//  - Per example: named-reg staging (6 float4) of 16-step chunks -> private
//    2-slot LDS ring -> per-lane label/blank column gather (+EPS hoisted).
//  - Per-block partials -> d_ws; 1-block tree-reduce writes the mean.

#define B_ 512
#define T_ 512
#define C_ 96
#define L_ 64
#define BLANK_ 95
#define EPSF 1e-7f
#define LN2F 0.69314718055994530942f
#define U_ 16               // time steps per chunk
#define CHF_ (U_ * C_)      // 1536 floats (6 KiB) per chunk
#define NCH_ (T_ / U_)      // 32 chunks

template <int CTRL>
__device__ __forceinline__ float dpp_mov(float x) {
    // bound_ctrl=true: invalid source lanes read 0 (identity for max of probs,
    // and exactly the "state -1 doesn't exist" boundary for wave_shr:1).
    return __int_as_float(
        __builtin_amdgcn_update_dpp(0, __float_as_int(x), CTRL, 0xF, 0xF, true));
}

// Full-wave max (64 lanes), all-VALU. Result returned wave-uniform (SGPR).
__device__ __forceinline__ float wave_max(float m) {
    m = fmaxf(m, dpp_mov<0x111>(m));  // row_shr:1
    m = fmaxf(m, dpp_mov<0x112>(m));  // row_shr:2
    m = fmaxf(m, dpp_mov<0x114>(m));  // row_shr:4
    m = fmaxf(m, dpp_mov<0x118>(m));  // row_shr:8   -> lane 15+16k = row max
    m = fmaxf(m, dpp_mov<0x142>(m));  // row_bcast:15
    m = fmaxf(m, dpp_mov<0x143>(m));  // row_bcast:31 -> lane 63 = wave max
    return __int_as_float(__builtin_amdgcn_readlane(__float_as_int(m), 63));
}

__launch_bounds__(64, 1)
__global__ void ctc_loss_kernel(const int* __restrict__ y_true,
                                const float* __restrict__ y_pred,
                                float* __restrict__ part) {
    __shared__ alignas(16) float smemA[2][CHF_];  // 12 KiB, slot = chunk & 1
    __shared__ alignas(16) float smemB[2][CHF_];  // 12 KiB
    const int blk = blockIdx.x;
    const int eA = 2 * blk, eB = 2 * blk + 1;
    const int lane = threadIdx.x;  // 0..63

    // ---- label metadata, both examples (R6-identical per example) ----
    const int yvA = y_true[eA * L_ + lane];
    const int yvB = y_true[eB * L_ + lane];
    const int lenA = __popcll(__ballot(yvA != -1));
    const int lenB = __popcll(__ballot(yvB != -1));
    const int labA = (yvA == -1) ? 0 : yvA;
    const int labB = (yvB == -1) ? 0 : yvB;
    const bool csA = (lane == 0) ? true : (labA != __shfl_up(labA, 1));
    const bool csB = (lane == 0) ? true : (labB != __shfl_up(labB, 1));

    const float4* gA = (const float4*)(y_pred + (size_t)eA * (T_ * C_));
    const float4* gB = (const float4*)(y_pred + (size_t)eB * (T_ * C_));

    // ---- staging registers: named scalars (spill-proof), 6 per example ----
    float4 sA0, sA1, sA2, sA3, sA4, sA5;
    float4 sB0, sB1, sB2, sB3, sB4, sB5;
    float elA[U_], ebA[U_], elB[U_], ebB[U_];
    float aeA, aoA, a1A;  int accA = 0;
    float aeB, aoB, a1B;  int accB = 0;

    auto loadA = [&](int c) {  // 6 x 1 KiB coalesced dwordx4
        const float4* g = gA + c * (CHF_ / 4) + lane;
        sA0 = g[0 * 64]; sA1 = g[1 * 64]; sA2 = g[2 * 64];
        sA3 = g[3 * 64]; sA4 = g[4 * 64]; sA5 = g[5 * 64];
    };
    auto loadB = [&](int c) {
        const float4* g = gB + c * (CHF_ / 4) + lane;
        sB0 = g[0 * 64]; sB1 = g[1 * 64]; sB2 = g[2 * 64];
        sB3 = g[3 * 64]; sB4 = g[4 * 64]; sB5 = g[5 * 64];
    };
    auto storeA = [&](int sl) {  // ds_write_b128, linear layout
        float4* s = (float4*)&smemA[sl][0] + lane;
        s[0 * 64] = sA0; s[1 * 64] = sA1; s[2 * 64] = sA2;
        s[3 * 64] = sA3; s[4 * 64] = sA4; s[5 * 64] = sA5;
    };
    auto storeB = [&](int sl) {
        float4* s = (float4*)&smemB[sl][0] + lane;
        s[0 * 64] = sB0; s[1 * 64] = sB1; s[2 * 64] = sB2;
        s[3 * 64] = sB3; s[4 * 64] = sB4; s[5 * 64] = sB5;
    };
    auto readA = [&](int sl) {  // per-lane column gathers (+EPS hoisted)
        const float* base = &smemA[sl][0];
#pragma unroll
        for (int k = 0; k < U_; ++k) {
            elA[k] = base[k * C_ + labA] + EPSF;
            ebA[k] = base[k * C_ + BLANK_] + EPSF;
        }
    };
    auto readB = [&](int sl) {
        const float* base = &smemB[sl][0];
#pragma unroll
        for (int k = 0; k < U_; ++k) {
            elB[k] = base[k * C_ + labB] + EPSF;
            ebB[k] = base[k * C_ + BLANK_] + EPSF;
        }
    };

    // ---- R2/R6's step, verbatim, per chain ----
    auto stepA = [&](float plv, float pbv) {
        const float po = dpp_mov<0x138>(aoA);
        const float pos = csA ? po : 0.0f;
        const float ne = (aeA + po) * pbv;
        const float no = (aoA + aeA + pos) * plv;
        a1A = (a1A + aoA) * pbv;
        aeA = ne; aoA = no;
    };
    auto stepB = [&](float plv, float pbv) {
        const float po = dpp_mov<0x138>(aoB);
        const float pos = csB ? po : 0.0f;
        const float ne = (aeB + po) * pbv;
        const float no = (aoB + aeB + pos) * plv;
        a1B = (a1B + aoB) * pbv;
        aeB = ne; aoB = no;
    };

    // ---- R2/R6's synchronous renorm, verbatim; cadence 8 FROZEN ----
    auto renA = [&]() {
        const float mv = wave_max(fmaxf(fmaxf(aeA, aoA), a1A));
        const int k = 96 - (((__float_as_int(mv) >> 23) & 0xFF) - 126);
        aeA = ldexpf(aeA, k); aoA = ldexpf(aoA, k); a1A = ldexpf(a1A, k);
        accA -= k;
    };
    auto renB = [&]() {
        const float mv = wave_max(fmaxf(fmaxf(aeB, aoB), a1B));
        const int k = 96 - (((__float_as_int(mv) >> 23) & 0xFF) - 126);
        aeB = ldexpf(aeB, k); aoB = ldexpf(aoB, k); a1B = ldexpf(a1B, k);
        accB -= k;
    };

    // Body for chunk c (c >= 1): gather chunk c (both), stage chunk c+1
    // regs->LDS (compiler-counted vmcnt), issue loads for chunk c+2, run
    // 16 interleaved steps with renorm at k=7,15 (t == 7 mod 8, as R6).
    auto body = [&](int c, bool ld) {
        readA(c & 1); readB(c & 1);
        storeA((c + 1) & 1); storeB((c + 1) & 1);
        if (ld) { loadA(c + 2); loadB(c + 2); }
#pragma unroll
        for (int k = 0; k < U_; ++k) {
            stepA(elA[k], ebA[k]);
            stepB(elB[k], ebB[k]);
            if ((k & 7) == 7) { renA(); renB(); }
        }
    };

    // ---- prologue ----
    loadA(0);  loadB(0);
    storeA(0); storeB(0);   // waits chunk-0 loads
    loadA(1);  loadB(1);
    readA(0);  readB(0);
    storeA(1); storeB(1);   // chunk 1 -> slot 1 (waits its loads)
    loadA(2);  loadB(2);

    // ---- chunk 0 inline: init (t=0) + steps 1..15, renorm at 7,15 ----
    aeA = (lane == 0) ? ebA[0] : 0.0f;  aoA = (lane == 0) ? elA[0] : 0.0f;
    aeB = (lane == 0) ? ebB[0] : 0.0f;  aoB = (lane == 0) ? elB[0] : 0.0f;
    a1A = 0.0f; a1B = 0.0f;
#pragma unroll
    for (int k = 1; k < U_; ++k) {
        stepA(elA[k], ebA[k]);
        stepB(elB[k], ebB[k]);
        if ((k & 7) == 7) { renA(); renB(); }
    }

    // ---- chunks 1..30 (last load: body 29 loads chunk 31) ----
    for (int c = 1; c <= 29; ++c) body(c, true);
    body(30, false);

    // ---- chunk 31: steps only (stored at body 30 into slot 1) ----
    readA(1); readB(1);
#pragma unroll
    for (int k = 0; k < U_; ++k) {
        stepA(elA[k], ebA[k]);
        stepB(elB[k], ebB[k]);
        if ((k & 7) == 7) { renA(); renB(); }
    }

    // ---- readout ----
    const float alA = __shfl(aoA, lenA - 1);
    const float abA = (lenA < L_) ? __shfl(aeA, lenA) : __shfl(a1A, 63);
    const float alB = __shfl(aoB, lenB - 1);
    const float abB = (lenB < L_) ? __shfl(aeB, lenB) : __shfl(a1B, 63);
    if (lane == 0) {
        part[eA] = -LN2F * (log2f(abA + alA) + (float)accA);
        part[eB] = -LN2F * (log2f(abB + alB) + (float)accB);
    }
}

// 1 block x 512 threads: tree-reduce the per-example losses, write the mean.
__launch_bounds__(512, 1)
__global__ void ctc_reduce_kernel(const float* __restrict__ part,
                                  float* __restrict__ out) {
    __shared__ float sm[B_];
    const int t = threadIdx.x;
    sm[t] = part[t];
    __syncthreads();
#pragma unroll
    for (int s = B_ / 2; s > 0; s >>= 1) {
        if (t < s) sm[t] += sm[t + s];
        __syncthreads();
    }
    if (t == 0) out[0] = sm[0] * (1.0f / B_);
}

extern "C" void kernel_launch(void* const* d_in, const int* in_sizes, int n_in,
                              void* d_out, int out_size, void* d_ws, size_t ws_size,
                              hipStream_t stream) {
    const int* y_true = (const int*)d_in[0];
    const float* y_pred = (const float*)d_in[1];
    float* part = (float*)d_ws;  // B_ floats of per-example losses
    float* out = (float*)d_out;
    ctc_loss_kernel<<<B_ / 2, 64, 0, stream>>>(y_true, y_pred, part);
    ctc_reduce_kernel<<<1, B_, 0, stream>>>(part, out);
}

// Round 9
// 152.506 us; speedup vs baseline: 1.0407x; 1.0407x over previous
//
#include <hip/hip_runtime.h>

// CTC loss forward DP (Keras ctc_batch_cost), mean over batch.
// B=512, T=512, C=96 (blank=95), L=64. Lane i owns extended states 2i and
// 2i+1; lane 63 also owns state 128.
//
// R11: FWD/BWD SPLIT — halve the serial depth. R10 showed wall time is the
// single-wave serial chain (2 chains/wave = 1.6x work-efficiency but net
// loss). CTC's DP is linear in alpha, so: wave 0 runs the verified forward
// recursion over t=0..255; wave 1 runs the adjoint (backward) recursion
// beta_t[s] = e[s]b[s] + e[s+1]b[s+1] + cs[s+2]e[s+2]b[s+2] from t=511 down
// to 255; P = sum_s alpha_255[s] * beta_255[s], combined in double.
//   - Per-wave math: cndmask-form steps, SYNCHRONOUS renorm every 8
//     (floor is load-bearing — frozen). Backward uses wave_shl:1 DPP
//     (mirror of forward's wave_shr:1), with lane63 feeding beta[128].
//   - Staging per wave: R6-verified named-reg (12 x float4) chunks of 32
//     rows -> private 2-slot LDS ring -> per-lane column gathers (+EPS).
//     Backward stages rows ascending, consumes them descending (static
//     reversed index).
//   - Partials -> d_ws; 1-block tree-reduce writes the mean (R9-verified).

#define B_ 512
#define T_ 512
#define C_ 96
#define L_ 64
#define BLANK_ 95
#define EPSF 1e-7f
#define LN2D 0.6931471805599453
#define U_ 32               // time steps per chunk
#define CHF_ (U_ * C_)      // 3072 floats (12 KiB) per chunk
#define NCH_ 8              // chunks per half (8 * 32 = 256 rows)

template <int CTRL>
__device__ __forceinline__ float dpp_mov(float x) {
    // bound_ctrl=true: invalid source lanes read 0 (exactly the "state
    // doesn't exist" boundary for wave_shr:1 / wave_shl:1).
    return __int_as_float(
        __builtin_amdgcn_update_dpp(0, __float_as_int(x), CTRL, 0xF, 0xF, true));
}

// Full-wave max (64 lanes), all-VALU. Result returned wave-uniform (SGPR).
__device__ __forceinline__ float wave_max(float m) {
    m = fmaxf(m, dpp_mov<0x111>(m));  // row_shr:1
    m = fmaxf(m, dpp_mov<0x112>(m));  // row_shr:2
    m = fmaxf(m, dpp_mov<0x114>(m));  // row_shr:4
    m = fmaxf(m, dpp_mov<0x118>(m));  // row_shr:8   -> lane 15+16k = row max
    m = fmaxf(m, dpp_mov<0x142>(m));  // row_bcast:15
    m = fmaxf(m, dpp_mov<0x143>(m));  // row_bcast:31 -> lane 63 = wave max
    return __int_as_float(__builtin_amdgcn_readlane(__float_as_int(m), 63));
}

__launch_bounds__(128, 1)
__global__ void ctc_loss_kernel(const int* __restrict__ y_true,
                                const float* __restrict__ y_pred,
                                float* __restrict__ part) {
    __shared__ alignas(16) float smF[2][CHF_];  // forward ring (24 KiB)
    __shared__ alignas(16) float smB[2][CHF_];  // backward ring (24 KiB)
    __shared__ float xchg[132];                 // beta states + accB
    const int b = blockIdx.x;
    const int wid = threadIdx.x >> 6;   // 0 = forward, 1 = backward
    const int lane = threadIdx.x & 63;

    // ---- label metadata (identical in both waves) ----
    const int yv = y_true[b * L_ + lane];
    const unsigned long long act = __ballot(yv != -1);
    const int len = __popcll(act);        // label length (32..64)
    const int lab = (yv == -1) ? 0 : yv;  // padded like the reference
    const int lab_prev = __shfl_up(lab, 1);
    const bool cs = (lane == 0) ? true : (lab != lab_prev);

    // forward-result registers kept live across the barrier for the combine
    float r_ae = 0.0f, r_ao = 0.0f, r_a1 = 0.0f;
    int r_acc = 0;

    if (wid == 0) {
        // ================= FORWARD: rows 0..255 (R6-verbatim math) =========
        const float4* g4 = (const float4*)(y_pred + (size_t)b * (T_ * C_));
        float4 s0, s1, s2, s3, s4, s5, s6, s7, s8, s9, s10, s11;
        float el[U_], eb[U_];
        float ae, ao, a1;
        int acc = 0;

        auto load_chunk = [&](int c) {  // 12 x 1 KiB coalesced dwordx4
            const float4* g = g4 + c * (CHF_ / 4) + lane;
            s0 = g[0 * 64];  s1 = g[1 * 64];  s2 = g[2 * 64];  s3 = g[3 * 64];
            s4 = g[4 * 64];  s5 = g[5 * 64];  s6 = g[6 * 64];  s7 = g[7 * 64];
            s8 = g[8 * 64];  s9 = g[9 * 64];  s10 = g[10 * 64]; s11 = g[11 * 64];
        };
        auto store_chunk = [&](int sl) {  // ds_write_b128, linear layout
            float4* s = (float4*)&smF[sl][0] + lane;
            s[0 * 64] = s0;  s[1 * 64] = s1;  s[2 * 64] = s2;  s[3 * 64] = s3;
            s[4 * 64] = s4;  s[5 * 64] = s5;  s[6 * 64] = s6;  s[7 * 64] = s7;
            s[8 * 64] = s8;  s[9 * 64] = s9;  s[10 * 64] = s10; s[11 * 64] = s11;
        };
        auto read_emis = [&](int sl) {  // per-lane column gathers (+EPS)
            const float* base = &smF[sl][0];
#pragma unroll
            for (int k = 0; k < U_; ++k) {
                el[k] = base[k * C_ + lab] + EPSF;
                eb[k] = base[k * C_ + BLANK_] + EPSF;
            }
        };
        auto step = [&](float plv, float pbv) {  // R2/R6 verbatim
            const float po = dpp_mov<0x138>(ao);  // alpha[2*lane-1]
            const float pos = cs ? po : 0.0f;
            const float ne = (ae + po) * pbv;
            const float no = (ao + ae + pos) * plv;
            a1 = (a1 + ao) * pbv;
            ae = ne;
            ao = no;
        };
        auto renorm = [&]() {  // R2/R6 verbatim; cadence 8 FROZEN
            const float mv = wave_max(fmaxf(fmaxf(ae, ao), a1));
            const int k = 96 - (((__float_as_int(mv) >> 23) & 0xFF) - 126);
            ae = ldexpf(ae, k); ao = ldexpf(ao, k); a1 = ldexpf(a1, k);
            acc -= k;
        };
        auto body = [&](int c, bool ld) {
            read_emis(c & 1);
            store_chunk((c + 1) & 1);
            if (ld) load_chunk(c + 2);
#pragma unroll
            for (int k = 0; k < U_; ++k) {
                step(el[k], eb[k]);
                if ((k & 7) == 7) renorm();
            }
        };

        load_chunk(0);
        store_chunk(0);   // waits chunk-0 loads
        load_chunk(1);
        read_emis(0);
        store_chunk(1);   // chunk 1 -> slot 1
        load_chunk(2);
        ae = (lane == 0) ? eb[0] : 0.0f;  // state 0 (blank), t=0
        ao = (lane == 0) ? el[0] : 0.0f;  // state 1 (label 0)
        a1 = 0.0f;
#pragma unroll
        for (int k = 1; k < U_; ++k) {
            step(el[k], eb[k]);
            if ((k & 7) == 7) renorm();
        }
        for (int c = 1; c <= 5; ++c) body(c, true);  // loads chunks 3..7
        body(6, false);
        read_emis(1);     // chunk 7
#pragma unroll
        for (int k = 0; k < U_; ++k) {
            step(el[k], eb[k]);
            if ((k & 7) == 7) renorm();
        }
        // alpha_255 now at scale ~2^96; shift to ~1 for the combine
        r_ae = ldexpf(ae, -96); r_ao = ldexpf(ao, -96); r_a1 = ldexpf(a1, -96);
        r_acc = acc + 96;
    } else {
        // ================= BACKWARD: rows 511..256 =========================
        // beta_{r-1}[2i]   = eb*b[2i] + el_i*b[2i+1]
        // beta_{r-1}[2i+1] = el_i*b[2i+1] + eb*b[2i+2] + cs[2i+3]*el_{i+1}*b[2i+3]
        // beta_{r-1}[128]  = eb*b[128]
        const float4* g4 = (const float4*)(y_pred + (size_t)b * (T_ * C_));
        const int labn = __shfl_down(lab, 1);          // lane i+1's label
        const int csn_i = __shfl_down((int)cs, 1);     // cs[2i+3]
        const float csn_f = csn_i ? 1.0f : 0.0f;
        const bool is63 = (lane == 63);
        float4 s0, s1, s2, s3, s4, s5, s6, s7, s8, s9, s10, s11;
        float el[U_], eb[U_], eq[U_];
        float be, bo, b1;
        int acc = -96;  // init beta = 1 stored as 2^96

        auto load_chunk = [&](int cc) {  // chunk cc = rows 480-32cc..511-32cc
            const float4* g = g4 + (480 - 32 * cc) * (C_ / 4) + lane;
            s0 = g[0 * 64];  s1 = g[1 * 64];  s2 = g[2 * 64];  s3 = g[3 * 64];
            s4 = g[4 * 64];  s5 = g[5 * 64];  s6 = g[6 * 64];  s7 = g[7 * 64];
            s8 = g[8 * 64];  s9 = g[9 * 64];  s10 = g[10 * 64]; s11 = g[11 * 64];
        };
        auto store_chunk = [&](int sl) {
            float4* s = (float4*)&smB[sl][0] + lane;
            s[0 * 64] = s0;  s[1 * 64] = s1;  s[2 * 64] = s2;  s[3 * 64] = s3;
            s[4 * 64] = s4;  s[5 * 64] = s5;  s[6 * 64] = s6;  s[7 * 64] = s7;
            s[8 * 64] = s8;  s[9 * 64] = s9;  s[10 * 64] = s10; s[11 * 64] = s11;
        };
        auto read_emis = [&](int sl) {  // step k consumes local row (31-k)
            const float* base = &smB[sl][0];
#pragma unroll
            for (int k = 0; k < U_; ++k) {
                const int rr = (U_ - 1 - k) * C_;
                el[k] = base[rr + lab] + EPSF;
                eb[k] = base[rr + BLANK_] + EPSF;
                eq[k] = csn_f * (base[rr + labn] + EPSF);
            }
        };
        auto step = [&](float el_, float eb_, float eq_) {
            const float bon = dpp_mov<0x130>(bo);   // beta[2i+3]; lane63 -> 0
            const float ber = dpp_mov<0x130>(be);   // beta[2i+2]; lane63 -> 0
            const float ben = is63 ? b1 : ber;      // lane63: beta[128]
            const float t = el_ * bo;
            const float nbe = eb_ * be + t;
            const float nbo = t + eb_ * ben + eq_ * bon;
            b1 = eb_ * b1;
            be = nbe;
            bo = nbo;
        };
        auto renorm = [&]() {
            const float mv = wave_max(fmaxf(fmaxf(be, bo), b1));
            const int k = 96 - (((__float_as_int(mv) >> 23) & 0xFF) - 126);
            be = ldexpf(be, k); bo = ldexpf(bo, k); b1 = ldexpf(b1, k);
            acc -= k;
        };
        auto body = [&](int c, bool ld) {
            read_emis(c & 1);
            store_chunk((c + 1) & 1);
            if (ld) load_chunk(c + 2);
#pragma unroll
            for (int k = 0; k < U_; ++k) {
                step(el[k], eb[k], eq[k]);
                if ((k & 7) == 7) renorm();
            }
        };

        load_chunk(0);
        store_chunk(0);
        load_chunk(1);
        read_emis(0);
        store_chunk(1);
        load_chunk(2);
        // init at t=511: beta=1 on states 2len-1 (and 2len)
        const float K96 = 0x1.0p96f;
        bo = (lane == len - 1) ? K96 : 0.0f;              // state 2len-1
        be = (len < L_ && lane == len) ? K96 : 0.0f;      // state 2len
        b1 = (len == L_ && is63) ? K96 : 0.0f;            // state 128
#pragma unroll
        for (int k = 0; k < U_; ++k) {   // chunk 0: rows 511..480
            step(el[k], eb[k], eq[k]);
            if ((k & 7) == 7) renorm();
        }
        for (int c = 1; c <= 5; ++c) body(c, true);  // loads chunks 3..7
        body(6, false);
        read_emis(1);     // chunk 7: rows 287..256
#pragma unroll
        for (int k = 0; k < U_; ++k) {
            step(el[k], eb[k], eq[k]);
            if ((k & 7) == 7) renorm();
        }
        // publish beta_255 (shifted to ~1) for the combine
        xchg[2 * lane] = ldexpf(be, -96);
        xchg[2 * lane + 1] = ldexpf(bo, -96);
        if (is63) {
            xchg[128] = ldexpf(b1, -96);
            xchg[129] = (float)(acc + 96);
        }
    }

    __syncthreads();  // single common barrier: beta visible to wave 0

    if (wid == 0) {
        // P = sum_s alpha_255[s] * beta_255[s], in double (no FTZ risk)
        double s = (double)r_ae * (double)xchg[2 * lane]
                 + (double)r_ao * (double)xchg[2 * lane + 1];
        if (lane == 63) s += (double)r_a1 * (double)xchg[128];
#pragma unroll
        for (int off = 32; off >= 1; off >>= 1) s += __shfl_xor(s, off);
        if (lane == 0) {
            const double accB = (double)xchg[129];
            part[b] = (float)(-LN2D * (log2(s) + (double)r_acc + accB));
        }
    }
}

// 1 block x 512 threads: tree-reduce the per-example losses, write the mean.
__launch_bounds__(512, 1)
__global__ void ctc_reduce_kernel(const float* __restrict__ part,
                                  float* __restrict__ out) {
    __shared__ float sm[B_];
    const int t = threadIdx.x;
    sm[t] = part[t];
    __syncthreads();
#pragma unroll
    for (int s = B_ / 2; s > 0; s >>= 1) {
        if (t < s) sm[t] += sm[t + s];
        __syncthreads();
    }
    if (t == 0) out[0] = sm[0] * (1.0f / B_);
}

extern "C" void kernel_launch(void* const* d_in, const int* in_sizes, int n_in,
                              void* d_out, int out_size, void* d_ws, size_t ws_size,
                              hipStream_t stream) {
    const int* y_true = (const int*)d_in[0];
    const float* y_pred = (const float*)d_in[1];
    float* part = (float*)d_ws;  // B_ floats of per-example losses
    float* out = (float*)d_out;
    ctc_loss_kernel<<<B_, 128, 0, stream>>>(y_true, y_pred, part);
    ctc_reduce_kernel<<<1, B_, 0, stream>>>(part, out);
}

// Round 11
// 151.575 us; speedup vs baseline: 1.0471x; 1.0061x over previous
//
#include <hip/hip_runtime.h>

// CTC loss forward DP (Keras ctc_batch_cost), mean over batch.
// B=512, T=512, C=96 (blank=95), L=64. One wave per example; lane i owns
// extended states 2i (blank) and 2i+1 (label i); lane 63 also owns state 128.
//
// R12 (resubmit — round 10 was an infra failure, kernel never ran):
// ROLL THE CHUNK LOOP — attack instruction fetch. R9/R10/R11 held
// kernel time ~constant (~42us) while serial depth (4x), wave count (4x) and
// memory strategy all varied; the invariant was instruction BYTES fetched
// per CU (fully-unrolled ~40-80KB bodies, streamed once, zero I$ reuse).
// This round: identical math/staging to R9 (frozen: cndmask step, sync
// renorm-8, named-reg staging -> 2-slot LDS ring, partials + tree-reduce),
// but chunks 1..15 are a REAL runtime loop (unroll(disable)): ~10KB emitted,
// 4KB body reused 15x from L1I. Per-example FP sequence bit-identical to R9.

#define B_ 512
#define T_ 512
#define C_ 96
#define L_ 64
#define BLANK_ 95
#define EPSF 1e-7f
#define LN2F 0.69314718055994530942f
#define U_ 32               // time steps per chunk
#define CHF_ (U_ * C_)      // 3072 floats (12 KiB) per chunk
#define NCH_ 16             // chunks

template <int CTRL>
__device__ __forceinline__ float dpp_mov(float x) {
    // bound_ctrl=true: invalid source lanes read 0 (identity for max of probs,
    // and exactly the "state -1 doesn't exist" boundary for wave_shr:1).
    return __int_as_float(
        __builtin_amdgcn_update_dpp(0, __float_as_int(x), CTRL, 0xF, 0xF, true));
}

// Full-wave max (64 lanes), all-VALU. Result returned wave-uniform (SGPR).
__device__ __forceinline__ float wave_max(float m) {
    m = fmaxf(m, dpp_mov<0x111>(m));  // row_shr:1
    m = fmaxf(m, dpp_mov<0x112>(m));  // row_shr:2
    m = fmaxf(m, dpp_mov<0x114>(m));  // row_shr:4
    m = fmaxf(m, dpp_mov<0x118>(m));  // row_shr:8   -> lane 15+16k = row max
    m = fmaxf(m, dpp_mov<0x142>(m));  // row_bcast:15
    m = fmaxf(m, dpp_mov<0x143>(m));  // row_bcast:31 -> lane 63 = wave max
    return __int_as_float(__builtin_amdgcn_readlane(__float_as_int(m), 63));
}

__launch_bounds__(64, 1)
__global__ void ctc_loss_kernel(const int* __restrict__ y_true,
                                const float* __restrict__ y_pred,
                                float* __restrict__ part) {
    __shared__ alignas(16) float smem[2][CHF_];  // 24 KiB, slot = chunk & 1
    const int b = blockIdx.x;
    const int lane = threadIdx.x;  // 0..63

    // ---- label metadata (identical to R2/R6/R9) ----
    const int yv = y_true[b * L_ + lane];
    const unsigned long long act = __ballot(yv != -1);
    const int len = __popcll(act);        // label length (32..64)
    const int lab = (yv == -1) ? 0 : yv;  // padded like the reference
    const int lab_prev = __shfl_up(lab, 1);
    const bool cs = (lane == 0) ? true : (lab != lab_prev);

    const float4* g4 = (const float4*)(y_pred + (size_t)b * (T_ * C_));

    // ---- staging registers: named scalars, cannot spill as an array ----
    float4 s0, s1, s2, s3, s4, s5, s6, s7, s8, s9, s10, s11;
    float el[U_], eb[U_];  // current chunk's emissions (+EPS pre-added)
    float a_even, a_odd, a128;
    int accum = 0;  // true_alpha = stored * 2^accum

    auto load_chunk = [&](int c) {  // 12 x 1 KiB coalesced dwordx4
        const float4* g = g4 + c * (CHF_ / 4) + lane;
        s0 = g[0 * 64];  s1 = g[1 * 64];  s2 = g[2 * 64];  s3 = g[3 * 64];
        s4 = g[4 * 64];  s5 = g[5 * 64];  s6 = g[6 * 64];  s7 = g[7 * 64];
        s8 = g[8 * 64];  s9 = g[9 * 64];  s10 = g[10 * 64]; s11 = g[11 * 64];
    };
    auto store_chunk = [&](int sl) {  // ds_write_b128, linear layout
        float4* s = (float4*)&smem[sl][0] + lane;
        s[0 * 64] = s0;  s[1 * 64] = s1;  s[2 * 64] = s2;  s[3 * 64] = s3;
        s[4 * 64] = s4;  s[5 * 64] = s5;  s[6 * 64] = s6;  s[7 * 64] = s7;
        s[8 * 64] = s8;  s[9 * 64] = s9;  s[10 * 64] = s10; s[11 * 64] = s11;
    };
    auto read_emis = [&](int sl) {  // per-lane column gathers (+EPS hoisted)
        const float* base = &smem[0][0] + sl * CHF_;
#pragma unroll
        for (int k = 0; k < U_; ++k) {
            el[k] = base[k * C_ + lab] + EPSF;     // label column (~2-way bank)
            eb[k] = base[k * C_ + BLANK_] + EPSF;  // uniform -> LDS broadcast
        }
    };

    // ---- R2/R6's step, verbatim ----
    auto step = [&](float plv, float pbv) {
        const float po = dpp_mov<0x138>(a_odd);  // wave_shr:1 -> alpha[2*lane-1]
        const float pos = cs ? po : 0.0f;
        const float ne = (a_even + po) * pbv;
        const float no = (a_odd + a_even + pos) * plv;
        a128 = (a128 + a_odd) * pbv;  // meaningful on lane 63 only
        a_even = ne;
        a_odd = no;
    };

    // ---- R2/R6's synchronous renorm, verbatim; cadence 8 FROZEN ----
    auto renorm = [&]() {
        const float mv = wave_max(fmaxf(fmaxf(a_even, a_odd), a128));
        const int e = ((__float_as_int(mv) >> 23) & 0xFF) - 126;
        const int k = 96 - e;
        a_even = ldexpf(a_even, k);
        a_odd  = ldexpf(a_odd, k);
        a128   = ldexpf(a128, k);
        accum -= k;
    };

    // ---- prologue + chunk 0 (as R9) ----
    load_chunk(0);
    store_chunk(0);   // waits chunk-0 loads
    load_chunk(1);
    read_emis(0);
    store_chunk(1);   // chunk 1 -> slot 1 (waits its loads)
    load_chunk(2);
    a_even = (lane == 0) ? eb[0] : 0.0f;  // state 0 (blank), t=0
    a_odd  = (lane == 0) ? el[0] : 0.0f;  // state 1 (label 0)
    a128 = 0.0f;
#pragma unroll
    for (int k = 1; k < U_; ++k) {
        step(el[k], eb[k]);
        if ((k & 7) == 7) renorm();
    }

    // ---- chunks 1..15: ROLLED loop (the experiment) ----
    // Invariant at top of iteration c: LDS slot (c&1) holds chunk c (stored
    // at iteration c-1 / prologue); regs hold chunk c+1 (loaded likewise).
#pragma clang loop unroll(disable)
    for (int c = 1; c <= 15; ++c) {
        read_emis(c & 1);
        if (c < 15) store_chunk((c + 1) & 1);
        if (c < 14) load_chunk(c + 2);
#pragma unroll
        for (int k = 0; k < U_; ++k) {
            step(el[k], eb[k]);
            if ((k & 7) == 7) renorm();
        }
    }

    // ---- readout: loss = -ln2 * (log2(a[2len] + a[2len-1]) + accum) ----
    const float al = __shfl(a_odd, len - 1);             // state 2len-1
    const float ab = (len < L_) ? __shfl(a_even, len)    // state 2len
                                : __shfl(a128, 63);      // state 128
    if (lane == 0) part[b] = -LN2F * (log2f(ab + al) + (float)accum);
}

// 1 block x 512 threads: tree-reduce the per-example losses, write the mean.
__launch_bounds__(512, 1)
__global__ void ctc_reduce_kernel(const float* __restrict__ part,
                                  float* __restrict__ out) {
    __shared__ float sm[B_];
    const int t = threadIdx.x;
    sm[t] = part[t];
    __syncthreads();
#pragma unroll
    for (int s = B_ / 2; s > 0; s >>= 1) {
        if (t < s) sm[t] += sm[t + s];
        __syncthreads();
    }
    if (t == 0) out[0] = sm[0] * (1.0f / B_);
}

extern "C" void kernel_launch(void* const* d_in, const int* in_sizes, int n_in,
                              void* d_out, int out_size, void* d_ws, size_t ws_size,
                              hipStream_t stream) {
    const int* y_true = (const int*)d_in[0];
    const float* y_pred = (const float*)d_in[1];
    float* part = (float*)d_ws;  // B_ floats of per-example losses
    float* out = (float*)d_out;
    ctc_loss_kernel<<<B_, 64, 0, stream>>>(y_true, y_pred, part);
    ctc_reduce_kernel<<<1, B_, 0, stream>>>(part, out);
}